// Round 7
// baseline (1034.410 us; speedup 1.0000x reference)
//
#include <hip/hip_runtime.h>
#include <hip/hip_fp16.h>

#define D 128
typedef unsigned int uint;
typedef unsigned short ushort;
typedef unsigned long long ull;

__device__ __forceinline__ float blo(uint u) { return __uint_as_float(u << 16); }
__device__ __forceinline__ float bhi(uint u) { return __uint_as_float(u & 0xffff0000u); }
__device__ __forceinline__ uint bpack(float a, float b) {
  uint ua = __float_as_uint(a), ub = __float_as_uint(b);
  ua = (ua + 0x7fffu + ((ua >> 16) & 1u)) >> 16;
  ub = (ub + 0x7fffu + ((ub >> 16) & 1u)) & 0xffff0000u;
  return ua | ub;
}
__device__ __forceinline__ float h2f(ushort h) { return __half2float(__ushort_as_half(h)); }
__device__ __forceinline__ ushort f2h(float f) { return __half_as_ushort(__float2half(f)); }
__device__ __forceinline__ int rdl(int v, int j) { return __builtin_amdgcn_readlane(v, j); }

#define PKSCALE 16777216.0f
#define PKMASK ((1ULL << 40) - 1)

// ---- no-LDS GEMM body (W streamed from L2), 32 rows/block, 4 rows/thread ----
struct DualHi { const uint4* p; };
__device__ __forceinline__ float4 ldx(const float* X, size_t i) {
  return ((const float4*)X)[i];
}
__device__ __forceinline__ float4 ldx(DualHi X, size_t i) {
  uint4 v = X.p[i];
  return make_float4(blo(v.z), bhi(v.z), blo(v.w), bhi(v.w));
}

template <typename XT>
__device__ __forceinline__ void gemm_body(int blk, XT X, const float* __restrict__ W,
                                          ushort* __restrict__ Y, int rows) {
  int tid = threadIdx.x;
  int c = tid & 31, rg = tid >> 5;
  int r0 = blk * 32 + rg * 4;
  float4 acc[4];
#pragma unroll
  for (int j = 0; j < 4; ++j) acc[j] = make_float4(0.f, 0.f, 0.f, 0.f);
  for (int k4 = 0; k4 < 32; ++k4) {
    float4 xv[4];
#pragma unroll
    for (int j = 0; j < 4; ++j) {
      int r = r0 + j;
      if (r >= rows) r = rows - 1;
      xv[j] = ldx(X, (size_t)r * 32 + k4);
    }
#pragma unroll
    for (int kk = 0; kk < 4; ++kk) {
      float4 wv = ((const float4*)W)[(k4 * 4 + kk) * 32 + c];
#pragma unroll
      for (int j = 0; j < 4; ++j) {
        float xs = kk == 0 ? xv[j].x : kk == 1 ? xv[j].y : kk == 2 ? xv[j].z : xv[j].w;
        acc[j].x = fmaf(xs, wv.x, acc[j].x);
        acc[j].y = fmaf(xs, wv.y, acc[j].y);
        acc[j].z = fmaf(xs, wv.z, acc[j].z);
        acc[j].w = fmaf(xs, wv.w, acc[j].w);
      }
    }
  }
#pragma unroll
  for (int j = 0; j < 4; ++j) {
    int r = r0 + j;
    if (r < rows)
      ((uint2*)(Y + (size_t)r * D))[c] =
          make_uint2(bpack(acc[j].x, acc[j].y), bpack(acc[j].z, acc[j].w));
  }
}

// ---- front: degree counts + dual-signal pack + gemm1, block-range roles ----
__global__ __launch_bounds__(256) void k_front(
    const int* __restrict__ uu, const int* __restrict__ ss, int EUS,
    const int* __restrict__ ei1, const int* __restrict__ ei2, const int* __restrict__ ei3,
    const float* __restrict__ ew1, const float* __restrict__ ew2,
    const float* __restrict__ ew3, int ES1, int ES2, int ES3,
    int* rp_u, int* rp_s, ull* gpk, int AM, int Etot,
    const float* __restrict__ ue, const float* __restrict__ se,
    uint4* __restrict__ UC, uint4* __restrict__ SC, int N, int M,
    int nbDeg, int nbPack, const float* __restrict__ W1, ushort* __restrict__ xw) {
  int b = blockIdx.x;
  if (b < nbDeg) {
    int e = b * 256 + threadIdx.x;
    if (e >= Etot) return;
    if (e < EUS) {
      atomicAdd(&rp_u[uu[e]], 1);
      atomicAdd(&rp_s[ss[e]], 1);
    } else {
      int t = e - EUS;
      const int* ei; const float* ew; int g, le, ESg;
      if (t < ES1) { g = 0; le = t; ei = ei1; ew = ew1; ESg = ES1; }
      else if (t < ES1 + ES2) { g = 1; le = t - ES1; ei = ei2; ew = ew2; ESg = ES2; }
      else { g = 2; le = t - ES1 - ES2; ei = ei3; ew = ew3; ESg = ES3; }
      int dst = ei[ESg + le];
      ull pk = (1ULL << 40) | (ull)(uint)(ew[le] * PKSCALE);
      atomicAdd(&gpk[(size_t)g * AM + dst], pk);
    }
  } else if (b < nbDeg + nbPack) {
    int g = (b - nbDeg) * 256 + threadIdx.x;
    int row = g >> 5, lane = g & 31;
    const float* src; uint4* dst; int r;
    if (row < N) { src = ue; dst = UC; r = row; }
    else if (row < N + M) { src = se; dst = SC; r = row - N; }
    else return;
    float4 v = ((const float4*)src)[(size_t)r * 32 + lane];
    uint a = bpack(v.x, v.y), bq = bpack(v.z, v.w);
    dst[(size_t)r * 32 + lane] = make_uint4(a, bq, a, bq);
  } else {
    gemm_body(b - nbDeg - nbPack, se, W1, xw, M);
  }
}

// ---- 5-segment scan (in-place counts -> exclusive starts) + dinv tables ----
__device__ __forceinline__ int block_excl(int my) {
  __shared__ int part[1024];
  int tid = threadIdx.x;
  part[tid] = my;
  __syncthreads();
  for (int off = 1; off < 1024; off <<= 1) {
    int v = tid >= off ? part[tid - off] : 0;
    __syncthreads();
    part[tid] += v;
    __syncthreads();
  }
  return tid == 0 ? 0 : part[tid - 1];
}

__global__ __launch_bounds__(1024) void k_scan5(int* rp_u, int* rp_s, int* grp,
                                                const ull* __restrict__ gpk,
                                                float* dinv_u, float* dinv_s,
                                                float* gdinv, int AM, int N, int M) {
  int b = blockIdx.x, tid = threadIdx.x;
  int n = b == 0 ? N : M;
  int chunk = (n + 1023) / 1024;
  int lo = tid * chunk;
  int hi = lo + chunk < n ? lo + chunk : n;
  if (lo > n) lo = n;
  if (hi < lo) hi = lo;
  if (b == 0) {
    int s = 0;
    for (int i = lo; i < hi; ++i) s += rp_u[i];
    int excl = block_excl(s);
    for (int i = lo; i < hi; ++i) {
      int c = rp_u[i];
      rp_u[i] = excl;
      excl += c;
      dinv_u[i] = c > 0 ? rsqrtf((float)c) : 0.f;
    }
  } else if (b == 1) {
    int s = 0;
    for (int i = lo; i < hi; ++i) s += rp_s[i];
    int excl = block_excl(s);
    for (int i = lo; i < hi; ++i) {
      int c = rp_s[i];
      rp_s[i] = excl;
      excl += c;
      dinv_s[i] = c > 0 ? rsqrtf((float)c) : 0.f;
    }
  } else {
    int g = b - 2;
    const ull* pc = gpk + (size_t)g * AM;
    int* rp = grp + (size_t)g * M;
    float* gd = gdinv + (size_t)g * AM;
    int s = 0;
    for (int i = lo; i < hi; ++i) s += (int)(pc[i] >> 40);
    int excl = block_excl(s);
    for (int i = lo; i < hi; ++i) {
      ull p = pc[i];
      int c = (int)(p >> 40);
      rp[i] = excl;
      excl += c;
      float d = (float)(p & PKMASK) * (1.0f / PKSCALE);
      gd[i] = d > 0.f ? rsqrtf(fmaxf(d, 1e-12f)) : 0.f;
    }
  }
}

// ---- both CSR fills, rp-as-cursor ----
__global__ void k_allfill(const int* __restrict__ uu, const int* __restrict__ ss, int EUS,
                          int* rp_u, int* rp_s, ushort* __restrict__ ue_s,
                          ushort* __restrict__ se_u, const int* __restrict__ ei1,
                          const int* __restrict__ ei2, const int* __restrict__ ei3,
                          const float* __restrict__ ew1, const float* __restrict__ ew2,
                          const float* __restrict__ ew3, int ES1, int ES2, int ES3,
                          const float* __restrict__ gdinv, int* grp,
                          uint* __restrict__ gsrc, int M, int AM, int Etot) {
  int e = blockIdx.x * blockDim.x + threadIdx.x;
  if (e >= Etot) return;
  if (e < EUS) {
    int ui = uu[e], si = ss[e];
    int p = atomicAdd(&rp_u[ui], 1);
    int q = atomicAdd(&rp_s[si], 1);
    ue_s[p] = (ushort)si;
    se_u[q] = (ushort)ui;
  } else {
    int t = e - EUS;
    const int* ei; const float* ew; int g, le, ESg, goff;
    if (t < ES1) { g = 0; le = t; ei = ei1; ew = ew1; ESg = ES1; goff = 0; }
    else if (t < ES1 + ES2) { g = 1; le = t - ES1; ei = ei2; ew = ew2; ESg = ES2; goff = ES1; }
    else { g = 2; le = t - ES1 - ES2; ei = ei3; ew = ew3; ESg = ES3; goff = ES1 + ES2; }
    int src = ei[le], dst = ei[ESg + le];
    float w = ew[le] * gdinv[(size_t)g * AM + src];
    int p = atomicAdd(&grp[(size_t)g * M + dst], 1);
    gsrc[goff + p] = (uint)src | ((uint)f2h(w) << 16);
  }
}

// ---- GCN gather body: wave per row, batched edge records + readlane ----
__device__ __forceinline__ void gcn_body(int gblk, const int* __restrict__ rpseg,
                                         const uint* __restrict__ erec,
                                         const float* __restrict__ dinv,
                                         const ushort* __restrict__ xw,
                                         const float* __restrict__ base,
                                         float* __restrict__ out, uint* outSC,
                                         float scale, int M) {
  int g = gblk * 256 + threadIdx.x;
  int row = g >> 6, l = g & 63;
  if (row >= M) return;
  int beg = row ? rpseg[row - 1] : 0;
  int end = rpseg[row];
  const uint* sv = (const uint*)xw;
  float2 sum = make_float2(0.f, 0.f);
  for (int base_i = beg; base_i < end; base_i += 64) {
    int nb = end - base_i;
    if (nb > 64) nb = 64;
    uint myrec = 0;
    if (base_i + l < end) myrec = erec[base_i + l];
#pragma unroll 4
    for (int j = 0; j < nb; ++j) {
      uint rec = (uint)rdl((int)myrec, j);
      int sr = (int)(rec & 0xffffu);
      float w = h2f((ushort)(rec >> 16));
      uint v = sv[(size_t)sr * 64 + l];
      sum.x = fmaf(w, blo(v), sum.x);
      sum.y = fmaf(w, bhi(v), sum.y);
    }
  }
  float sc = dinv[row] * scale;
  size_t lf = (size_t)row * 64 + l;
  float2 b = ((const float2*)base)[lf];
  float2 o = make_float2(fmaf(sc, sum.x, b.x), fmaf(sc, sum.y, b.y));
  ((float2*)out)[lf] = o;
  if (outSC) outSC[(size_t)row * 128 + 4 * (l >> 1) + (l & 1)] = bpack(o.x, o.y);
}

__global__ __launch_bounds__(256) void k_gcn_gather(
    const int* __restrict__ rpseg, const uint* __restrict__ erec,
    const float* __restrict__ dinv, const ushort* __restrict__ xw,
    const float* __restrict__ base, float* __restrict__ out, uint* outSC,
    float scale, int M) {
  gcn_body(blockIdx.x, rpseg, erec, dinv, xw, base, out, outSC, scale, M);
}

// ---- tail: gemm3 + gg2 in one dispatch ----
__global__ __launch_bounds__(256) void k_tail(
    int gG, DualHi X3, const float* __restrict__ W3, ushort* __restrict__ xw3, int rows,
    const int* __restrict__ rpseg, const uint* __restrict__ erec,
    const float* __restrict__ dinv, const ushort* __restrict__ xw2,
    float* __restrict__ o_so2, float scale, int M) {
  int b = blockIdx.x;
  if (b < gG) gemm_body(b, X3, W3, xw3, rows);
  else gcn_body(b - gG, rpseg, erec, dinv, xw2, o_so2, o_so2, (uint*)nullptr, scale, M);
}

// ---- fused dual-signal bipartite layer: wave per row, readlane broadcast ----
__global__ __launch_bounds__(256) void k_prop_dual(
    const int* __restrict__ rp_u, const ushort* __restrict__ ue_s,
    const int* __restrict__ rp_s, const ushort* __restrict__ se_u,
    const float* __restrict__ dinv_u, const float* __restrict__ dinv_s,
    const uint2* __restrict__ SCin, const uint2* __restrict__ UCin,
    uint2* __restrict__ SCout, uint2* __restrict__ UCout,
    const float* __restrict__ base_u1, const float* __restrict__ base_u2,
    const float* __restrict__ base_s1, const float* __restrict__ base_s2,
    float* __restrict__ acc_u1, float* __restrict__ acc_u2,
    float* __restrict__ acc_s1, float* __restrict__ acc_s2,
    float* dup_u2, float* dup_s2, float fs, int N, int M,
    int nbProp, const float* __restrict__ Xg, const float* __restrict__ Wg,
    ushort* __restrict__ xwg, int Mg) {
  int b = blockIdx.x;
  if (b >= nbProp) {
    if (Wg) gemm_body(b - nbProp, Xg, Wg, xwg, Mg);
    return;
  }
  int g = b * 256 + threadIdx.x;
  int row = g >> 6, l = g & 63;
  const int* rp; const ushort* ei; const float* dopp; const uint2* tbl;
  uint2* otbl; const float *b1, *b2; float *a1, *a2, *d2; float wrow; int r;
  if (row < N) {
    r = row; rp = rp_u; ei = ue_s; dopp = dinv_s; tbl = SCin; otbl = UCout;
    b1 = base_u1; b2 = base_u2; a1 = acc_u1; a2 = acc_u2; d2 = dup_u2;
    wrow = dinv_u[r];
  } else if (row < N + M) {
    r = row - N; rp = rp_s; ei = se_u; dopp = dinv_u; tbl = UCin; otbl = SCout;
    b1 = base_s1; b2 = base_s2; a1 = acc_s1; a2 = acc_s2; d2 = dup_s2;
    wrow = dinv_s[r];
  } else return;
  int beg = r ? rp[r - 1] : 0;
  int end = rp[r];
  float4 sum = make_float4(0.f, 0.f, 0.f, 0.f);
  for (int base_i = beg; base_i < end; base_i += 64) {
    int nb = end - base_i;
    if (nb > 64) nb = 64;
    int myidx = 0;
    if (base_i + l < end) myidx = ei[base_i + l];
    float myw = dopp[myidx];
#pragma unroll 4
    for (int j = 0; j < nb; ++j) {
      int idx = rdl(myidx, j);
      float w = wrow * __uint_as_float((uint)rdl((int)__float_as_uint(myw), j));
      uint2 v = tbl[(size_t)idx * 64 + l];
      sum.x = fmaf(w, blo(v.x), sum.x); sum.y = fmaf(w, bhi(v.x), sum.y);
      sum.z = fmaf(w, blo(v.y), sum.z); sum.w = fmaf(w, bhi(v.y), sum.w);
    }
  }
  if (otbl)
    otbl[(size_t)r * 64 + l] = make_uint2(bpack(sum.x, sum.y), bpack(sum.z, sum.w));
  int j = l >> 1, sig = l & 1;
  size_t lf = (size_t)r * 32 + j;
  const float* bb = sig ? b2 : b1;
  float* a = sig ? a2 : a1;
  float4 vb = ((const float4*)bb)[lf];
  float4 o = make_float4((vb.x + sum.x) * fs, (vb.y + sum.y) * fs,
                         (vb.z + sum.z) * fs, (vb.w + sum.w) * fs);
  ((float4*)a)[lf] = o;
  if (sig && d2) ((float4*)d2)[lf] = o;
}

extern "C" void kernel_launch(void* const* d_in, const int* in_sizes, int n_in,
                              void* d_out, int out_size, void* d_ws, size_t ws_size,
                              hipStream_t stream) {
  const float* spot_emb = (const float*)d_in[0];
  const float* user_emb = (const float*)d_in[1];
  const float* W1 = (const float*)d_in[2];
  const float* W2 = (const float*)d_in[3];
  const float* W3 = (const float*)d_in[4];
  const float* ew1 = (const float*)d_in[5];
  const float* ew2 = (const float*)d_in[6];
  const float* ew3 = (const float*)d_in[7];
  const int* us = (const int*)d_in[8];
  const int* ei1 = (const int*)d_in[9];
  const int* ei2 = (const int*)d_in[10];
  const int* ei3 = (const int*)d_in[11];

  const int M = in_sizes[0] / D;
  const int N = in_sizes[1] / D;
  const int EUS = in_sizes[8] / 2;
  const int ES1 = in_sizes[9] / 2;
  const int ES2 = in_sizes[10] / 2;
  const int ES3 = in_sizes[11] / 2;
  const int EStot = ES1 + ES2 + ES3;
  const int Etot = EUS + EStot;

  const int* uu = us;
  const int* ss = us + EUS;

  const size_t MD = (size_t)M * D, ND = (size_t)N * D;
  const int AM = (int)((M + 63) & ~63);

  float* cur = (float*)d_ws;
  auto take = [&](size_t n) { float* p = cur; cur += (n + 63) & ~(size_t)63; return p; };

  // contiguous zero group: count/cursor arrays
  int* rp_u = (int*)take(N);
  int* rp_s = (int*)take(M);
  int* grp = (int*)take((size_t)3 * M);
  float* zero_end = cur;
  float* dinv_u = take(N);
  float* dinv_s = take(M);
  float* gdinv = take((size_t)3 * AM);
  ushort* ue_s = (ushort*)take(EUS / 2 + 32);
  ushort* se_u = (ushort*)take(EUS / 2 + 32);
  uint* gsrc = (uint*)take(EStot);
  ushort* xw = (ushort*)take(MD / 2);
  uint2* UC_A = (uint2*)take(ND);
  uint2* UC_B = (uint2*)take(ND);
  uint2* SC_A = (uint2*)take(MD);
  uint2* SC_B = (uint2*)take(MD);

  ull* gpk = (ull*)UC_B;          // alias: gpk dead before UC_B first written
  ushort* xw3 = (ushort*)UC_A;    // alias: UC_A dead after prop3

  float* out = (float*)d_out;
  float* o_so1 = out;
  float* o_uo1 = o_so1 + MD;
  float* o_so2 = o_uo1 + ND;
  float* o_uo2 = o_so2 + MD;
  float* o_so3 = o_uo2 + ND;
  float* o_uo3 = o_so3 + MD;

  const int B = 256;
  auto gr = [&](size_t work) { return (int)((work + B - 1) / B); };
  const int nbDeg = gr(Etot);
  const int nbPack = gr((size_t)(N + M) * 32);
  const int gProp = gr((size_t)(N + M) * 64);
  const int gM64 = gr((size_t)M * 64);
  const int gG = (M + 31) / 32;
  float* nulf = (float*)nullptr;

  hipMemsetAsync(rp_u, 0, (char*)zero_end - (char*)rp_u, stream);
  hipMemsetAsync(gpk, 0, (size_t)3 * AM * sizeof(ull), stream);

  // degrees + dual-pack + gemm1 (xw1) in one dispatch
  k_front<<<nbDeg + nbPack + gG, B, 0, stream>>>(
      uu, ss, EUS, ei1, ei2, ei3, ew1, ew2, ew3, ES1, ES2, ES3,
      rp_u, rp_s, gpk, AM, Etot, user_emb, spot_emb, (uint4*)UC_A, (uint4*)SC_A,
      N, M, nbDeg, nbPack, W1, xw);
  // exclusive starts + dinv tables
  k_scan5<<<5, 1024, 0, stream>>>(rp_u, rp_s, grp, gpk, dinv_u, dinv_s, gdinv, AM, N, M);
  // both CSR fills (rp-as-cursor)
  k_allfill<<<gr(Etot), B, 0, stream>>>(uu, ss, EUS, rp_u, rp_s, ue_s, se_u,
                                        ei1, ei2, ei3, ew1, ew2, ew3, ES1, ES2, ES3,
                                        gdinv, grp, gsrc, M, AM, Etot);

  // branch-1 conv: o_so1 = spot_emb + cat1 (also refreshes SC_A sig1)
  k_gcn_gather<<<gM64, B, 0, stream>>>(grp, gsrc, gdinv, xw, spot_emb, o_so1,
                                       (uint*)SC_A, 1.0f, M);

  // prop layer 1 (+ gemm2 -> xw, hidden in the same dispatch)
  k_prop_dual<<<gProp + gG, B, 0, stream>>>(rp_u, ue_s, rp_s, se_u, dinv_u, dinv_s,
                                            SC_A, UC_A, SC_B, UC_B,
                                            user_emb, user_emb, o_so1, spot_emb,
                                            o_uo1, o_uo2, o_so1, o_so2,
                                            nulf, nulf, 1.0f, N, M,
                                            gProp, spot_emb, W2, xw, M);
  // prop layer 2
  k_prop_dual<<<gProp, B, 0, stream>>>(rp_u, ue_s, rp_s, se_u, dinv_u, dinv_s,
                                       SC_B, UC_B, SC_A, UC_A,
                                       o_uo1, o_uo2, o_so1, o_so2,
                                       o_uo1, o_uo2, o_so1, o_so2,
                                       nulf, nulf, 1.0f, N, M,
                                       gProp, nulf, nulf, (ushort*)nullptr, M);
  // prop layer 3 (emits fin_s into SC_B sig2; p duplicated to so3/uo3)
  k_prop_dual<<<gProp, B, 0, stream>>>(rp_u, ue_s, rp_s, se_u, dinv_u, dinv_s,
                                       SC_A, UC_A, SC_B, (uint2*)nullptr,
                                       o_uo1, o_uo2, o_so1, o_so2,
                                       o_uo1, o_uo2, o_so1, o_so2,
                                       o_uo3, o_so3, 0.25f, N, M,
                                       gProp, nulf, nulf, (ushort*)nullptr, M);

  // tail: gemm3 (fin_s -> xw3) + gg2 (xw -> o_so2) in one dispatch
  k_tail<<<gG + gM64, B, 0, stream>>>(gG, DualHi{(const uint4*)SC_B}, W3, xw3, M,
                                      grp + M, gsrc + ES1, gdinv + AM, xw,
                                      o_so2, 0.25f, M);
  // branch 3: so3 += cat3/4
  k_gcn_gather<<<gM64, B, 0, stream>>>(grp + 2 * M, gsrc + ES1 + ES2, gdinv + 2 * AM,
                                       xw3, o_so3, o_so3, (uint*)nullptr, 0.25f, M);
}

// Round 8
// 928.786 us; speedup vs baseline: 1.1137x; 1.1137x over previous
//
#include <hip/hip_runtime.h>
#include <hip/hip_fp16.h>

#define D 128
typedef unsigned int uint;
typedef unsigned short ushort;
typedef unsigned long long ull;

__device__ __forceinline__ float blo(uint u) { return __uint_as_float(u << 16); }
__device__ __forceinline__ float bhi(uint u) { return __uint_as_float(u & 0xffff0000u); }
__device__ __forceinline__ uint bpack(float a, float b) {
  uint ua = __float_as_uint(a), ub = __float_as_uint(b);
  ua = (ua + 0x7fffu + ((ua >> 16) & 1u)) >> 16;
  ub = (ub + 0x7fffu + ((ub >> 16) & 1u)) & 0xffff0000u;
  return ua | ub;
}
__device__ __forceinline__ float h2f(ushort h) { return __half2float(__ushort_as_half(h)); }
__device__ __forceinline__ ushort f2h(float f) { return __half_as_ushort(__float2half(f)); }

#define PKSCALE 16777216.0f
#define PKMASK ((1ULL << 40) - 1)

// ---- no-LDS GEMM body (W streamed from L2), 32 rows/block, 4 rows/thread ----
struct DualHi { const uint4* p; };
__device__ __forceinline__ float4 ldx(const float* X, size_t i) {
  return ((const float4*)X)[i];
}
__device__ __forceinline__ float4 ldx(DualHi X, size_t i) {
  uint4 v = X.p[i];
  return make_float4(blo(v.z), bhi(v.z), blo(v.w), bhi(v.w));
}

template <typename XT>
__device__ __forceinline__ void gemm_body(int blk, XT X, const float* __restrict__ W,
                                          ushort* __restrict__ Y, int rows) {
  int tid = threadIdx.x;
  int c = tid & 31, rg = tid >> 5;
  int r0 = blk * 32 + rg * 4;
  float4 acc[4];
#pragma unroll
  for (int j = 0; j < 4; ++j) acc[j] = make_float4(0.f, 0.f, 0.f, 0.f);
  for (int k4 = 0; k4 < 32; ++k4) {
    float4 xv[4];
#pragma unroll
    for (int j = 0; j < 4; ++j) {
      int r = r0 + j;
      if (r >= rows) r = rows - 1;
      xv[j] = ldx(X, (size_t)r * 32 + k4);
    }
#pragma unroll
    for (int kk = 0; kk < 4; ++kk) {
      float4 wv = ((const float4*)W)[(k4 * 4 + kk) * 32 + c];
#pragma unroll
      for (int j = 0; j < 4; ++j) {
        float xs = kk == 0 ? xv[j].x : kk == 1 ? xv[j].y : kk == 2 ? xv[j].z : xv[j].w;
        acc[j].x = fmaf(xs, wv.x, acc[j].x);
        acc[j].y = fmaf(xs, wv.y, acc[j].y);
        acc[j].z = fmaf(xs, wv.z, acc[j].z);
        acc[j].w = fmaf(xs, wv.w, acc[j].w);
      }
    }
  }
#pragma unroll
  for (int j = 0; j < 4; ++j) {
    int r = r0 + j;
    if (r < rows)
      ((uint2*)(Y + (size_t)r * D))[c] =
          make_uint2(bpack(acc[j].x, acc[j].y), bpack(acc[j].z, acc[j].w));
  }
}

// ---- front: degree counts + gemm1, block-range roles ----
__global__ __launch_bounds__(256) void k_front(
    const int* __restrict__ uu, const int* __restrict__ ss, int EUS,
    const int* __restrict__ ei1, const int* __restrict__ ei2, const int* __restrict__ ei3,
    const float* __restrict__ ew1, const float* __restrict__ ew2,
    const float* __restrict__ ew3, int ES1, int ES2, int ES3,
    int* rp_u, int* rp_s, ull* gpk, int AM, int Etot, int nbDeg,
    const float* __restrict__ se, const float* __restrict__ W1,
    ushort* __restrict__ xw, int M) {
  int b = blockIdx.x;
  if (b < nbDeg) {
    int e = b * 256 + threadIdx.x;
    if (e >= Etot) return;
    if (e < EUS) {
      atomicAdd(&rp_u[uu[e]], 1);
      atomicAdd(&rp_s[ss[e]], 1);
    } else {
      int t = e - EUS;
      const int* ei; const float* ew; int g, le, ESg;
      if (t < ES1) { g = 0; le = t; ei = ei1; ew = ew1; ESg = ES1; }
      else if (t < ES1 + ES2) { g = 1; le = t - ES1; ei = ei2; ew = ew2; ESg = ES2; }
      else { g = 2; le = t - ES1 - ES2; ei = ei3; ew = ew3; ESg = ES3; }
      int dst = ei[ESg + le];
      ull pk = (1ULL << 40) | (ull)(uint)(ew[le] * PKSCALE);
      atomicAdd(&gpk[(size_t)g * AM + dst], pk);
    }
  } else {
    gemm_body(b - nbDeg, se, W1, xw, M);
  }
}

// ---- 5-segment scan (in-place counts -> exclusive starts) + dinv tables ----
__device__ __forceinline__ int block_excl(int my) {
  __shared__ int part[1024];
  int tid = threadIdx.x;
  part[tid] = my;
  __syncthreads();
  for (int off = 1; off < 1024; off <<= 1) {
    int v = tid >= off ? part[tid - off] : 0;
    __syncthreads();
    part[tid] += v;
    __syncthreads();
  }
  return tid == 0 ? 0 : part[tid - 1];
}

__global__ __launch_bounds__(1024) void k_scan5(int* rp_u, int* rp_s, int* grp,
                                                const ull* __restrict__ gpk,
                                                float* dinv_u, float* dinv_s,
                                                float* gdinv, int AM, int N, int M) {
  int b = blockIdx.x, tid = threadIdx.x;
  int n = b == 0 ? N : M;
  int chunk = (n + 1023) / 1024;
  int lo = tid * chunk;
  int hi = lo + chunk < n ? lo + chunk : n;
  if (lo > n) lo = n;
  if (hi < lo) hi = lo;
  if (b == 0) {
    int s = 0;
    for (int i = lo; i < hi; ++i) s += rp_u[i];
    int excl = block_excl(s);
    for (int i = lo; i < hi; ++i) {
      int c = rp_u[i];
      rp_u[i] = excl;
      excl += c;
      dinv_u[i] = c > 0 ? rsqrtf((float)c) : 0.f;
    }
  } else if (b == 1) {
    int s = 0;
    for (int i = lo; i < hi; ++i) s += rp_s[i];
    int excl = block_excl(s);
    for (int i = lo; i < hi; ++i) {
      int c = rp_s[i];
      rp_s[i] = excl;
      excl += c;
      dinv_s[i] = c > 0 ? rsqrtf((float)c) : 0.f;
    }
  } else {
    int g = b - 2;
    const ull* pc = gpk + (size_t)g * AM;
    int* rp = grp + (size_t)g * M;
    float* gd = gdinv + (size_t)g * AM;
    int s = 0;
    for (int i = lo; i < hi; ++i) s += (int)(pc[i] >> 40);
    int excl = block_excl(s);
    for (int i = lo; i < hi; ++i) {
      ull p = pc[i];
      int c = (int)(p >> 40);
      rp[i] = excl;
      excl += c;
      float d = (float)(p & PKMASK) * (1.0f / PKSCALE);
      gd[i] = d > 0.f ? rsqrtf(fmaxf(d, 1e-12f)) : 0.f;
    }
  }
}

// ---- fills (rp-as-cursor) + dinv-scaled dual pack, one dispatch ----
__global__ __launch_bounds__(256) void k_allfill(
    const int* __restrict__ uu, const int* __restrict__ ss, int EUS,
    int* rp_u, int* rp_s, ushort* __restrict__ ue_s, ushort* __restrict__ se_u,
    const int* __restrict__ ei1, const int* __restrict__ ei2, const int* __restrict__ ei3,
    const float* __restrict__ ew1, const float* __restrict__ ew2,
    const float* __restrict__ ew3, int ES1, int ES2, int ES3,
    const float* __restrict__ gdinv, int* grp, uint* __restrict__ gsrc,
    int M, int AM, int Etot, int nbFill,
    const float* __restrict__ ue, const float* __restrict__ se,
    const float* __restrict__ dinv_u, const float* __restrict__ dinv_s,
    uint4* __restrict__ UC, uint4* __restrict__ SC, int N) {
  int b = blockIdx.x;
  if (b < nbFill) {
    int e = b * 256 + threadIdx.x;
    if (e >= Etot) return;
    if (e < EUS) {
      int ui = uu[e], si = ss[e];
      int p = atomicAdd(&rp_u[ui], 1);
      int q = atomicAdd(&rp_s[si], 1);
      ue_s[p] = (ushort)si;
      se_u[q] = (ushort)ui;
    } else {
      int t = e - EUS;
      const int* ei; const float* ew; int g, le, ESg, goff;
      if (t < ES1) { g = 0; le = t; ei = ei1; ew = ew1; ESg = ES1; goff = 0; }
      else if (t < ES1 + ES2) { g = 1; le = t - ES1; ei = ei2; ew = ew2; ESg = ES2; goff = ES1; }
      else { g = 2; le = t - ES1 - ES2; ei = ei3; ew = ew3; ESg = ES3; goff = ES1 + ES2; }
      int src = ei[le], dst = ei[ESg + le];
      float w = ew[le] * gdinv[(size_t)g * AM + src];
      int p = atomicAdd(&grp[(size_t)g * M + dst], 1);
      gsrc[goff + p] = (uint)src | ((uint)f2h(w) << 16);
    }
  } else {
    int g = (b - nbFill) * 256 + threadIdx.x;
    int row = g >> 5, lane = g & 31;
    const float* src; uint4* dst; float d; int r;
    if (row < N) { src = ue; dst = UC; r = row; d = dinv_u[r]; }
    else if (row < N + M) { src = se; dst = SC; r = row - N; d = dinv_s[r]; }
    else return;
    float4 v = ((const float4*)src)[(size_t)r * 32 + lane];
    uint a = bpack(d * v.x, d * v.y), bq = bpack(d * v.z, d * v.w);
    dst[(size_t)r * 32 + lane] = make_uint4(a, bq, a, bq);
  }
}

// ---- GCN gather body: wave per row, plain broadcast loop ----
__device__ __forceinline__ void gcn_body(int gblk, const int* __restrict__ rpseg,
                                         const uint* __restrict__ erec,
                                         const float* __restrict__ dinv,
                                         const ushort* __restrict__ xw,
                                         const float* __restrict__ base,
                                         float* __restrict__ out, uint* outSC,
                                         const float* __restrict__ sdinv,
                                         float scale, int M) {
  int g = gblk * 256 + threadIdx.x;
  int row = g >> 6, l = g & 63;
  if (row >= M) return;
  int beg = row ? rpseg[row - 1] : 0;
  int end = rpseg[row];
  const uint* sv = (const uint*)xw;
  float2 sum = make_float2(0.f, 0.f);
#pragma unroll 4
  for (int i = beg; i < end; ++i) {
    uint rec = erec[i];
    int sr = (int)(rec & 0xffffu);
    float w = h2f((ushort)(rec >> 16));
    uint v = sv[(size_t)sr * 64 + l];
    sum.x = fmaf(w, blo(v), sum.x);
    sum.y = fmaf(w, bhi(v), sum.y);
  }
  float sc = dinv[row] * scale;
  size_t lf = (size_t)row * 64 + l;
  float2 b = ((const float2*)base)[lf];
  float2 o = make_float2(fmaf(sc, sum.x, b.x), fmaf(sc, sum.y, b.y));
  ((float2*)out)[lf] = o;
  if (outSC) {
    float sd = sdinv[row];
    outSC[(size_t)row * 128 + 4 * (l >> 1) + (l & 1)] = bpack(sd * o.x, sd * o.y);
  }
}

__global__ __launch_bounds__(256) void k_gcn_gather(
    const int* __restrict__ rpseg, const uint* __restrict__ erec,
    const float* __restrict__ dinv, const ushort* __restrict__ xw,
    const float* __restrict__ base, float* __restrict__ out, uint* outSC,
    const float* __restrict__ sdinv, float scale, int M) {
  gcn_body(blockIdx.x, rpseg, erec, dinv, xw, base, out, outSC, sdinv, scale, M);
}

// ---- tail: gemm3 + gg2 in one dispatch ----
__global__ __launch_bounds__(256) void k_tail(
    int gG, DualHi X3, const float* __restrict__ W3, ushort* __restrict__ xw3, int rows,
    const int* __restrict__ rpseg, const uint* __restrict__ erec,
    const float* __restrict__ dinv, const ushort* __restrict__ xw2,
    float* __restrict__ o_so2, float scale, int M) {
  int b = blockIdx.x;
  if (b < gG) gemm_body(b, X3, W3, xw3, rows);
  else gcn_body(b - gG, rpseg, erec, dinv, xw2, o_so2, o_so2, (uint*)nullptr,
                (const float*)nullptr, scale, M);
}

// ---- fused dual-signal bipartite layer: wave/row, factorized dinv (no per-edge w)
__global__ __launch_bounds__(256) void k_prop_dual(
    const int* __restrict__ rp_u, const ushort* __restrict__ ue_s,
    const int* __restrict__ rp_s, const ushort* __restrict__ se_u,
    const float* __restrict__ dinv_u, const float* __restrict__ dinv_s,
    const uint2* __restrict__ SCin, const uint2* __restrict__ UCin,
    uint2* __restrict__ SCout, uint2* __restrict__ UCout,
    const float* __restrict__ base_u1, const float* __restrict__ base_u2,
    const float* __restrict__ base_s1, const float* __restrict__ base_s2,
    float* __restrict__ acc_u1, float* __restrict__ acc_u2,
    float* __restrict__ acc_s1, float* __restrict__ acc_s2,
    float* dup_u2, float* dup_s2, float fs, int finalLayer, int N, int M,
    int nbProp, const float* __restrict__ Xg, const float* __restrict__ Wg,
    ushort* __restrict__ xwg, int Mg) {
  int b = blockIdx.x;
  if (b >= nbProp) {
    if (Wg) gemm_body(b - nbProp, Xg, Wg, xwg, Mg);
    return;
  }
  int g = b * 256 + threadIdx.x;
  int row = g >> 6, l = g & 63;
  const int* rp; const ushort* ei; const uint2* tbl;
  uint2* otbl; const float *b1, *b2; float *a1, *a2, *d2; float wrow; int r;
  if (row < N) {
    r = row; rp = rp_u; ei = ue_s; tbl = SCin; otbl = UCout;
    b1 = base_u1; b2 = base_u2; a1 = acc_u1; a2 = acc_u2; d2 = dup_u2;
    wrow = dinv_u[r];
  } else if (row < N + M) {
    r = row - N; rp = rp_s; ei = se_u; tbl = UCin; otbl = SCout;
    b1 = base_s1; b2 = base_s2; a1 = acc_s1; a2 = acc_s2; d2 = dup_s2;
    wrow = dinv_s[r];
  } else return;
  int beg = r ? rp[r - 1] : 0;
  int end = rp[r];
  float4 sum = make_float4(0.f, 0.f, 0.f, 0.f);
#pragma unroll 4
  for (int i = beg; i < end; ++i) {
    int idx = ei[i];
    uint2 v = tbl[(size_t)idx * 64 + l];
    sum.x += blo(v.x); sum.y += bhi(v.x);
    sum.z += blo(v.y); sum.w += bhi(v.y);
  }
  if (otbl) {
    float f = finalLayer ? wrow : wrow * wrow;  // final: raw x; else y = dinv*x
    otbl[(size_t)r * 64 + l] =
        make_uint2(bpack(f * sum.x, f * sum.y), bpack(f * sum.z, f * sum.w));
  }
  int j = l >> 1, sig = l & 1;
  size_t lf = (size_t)r * 32 + j;
  const float* bb = sig ? b2 : b1;
  float* a = sig ? a2 : a1;
  float4 vb = ((const float4*)bb)[lf];
  float4 o = make_float4((vb.x + wrow * sum.x) * fs, (vb.y + wrow * sum.y) * fs,
                         (vb.z + wrow * sum.z) * fs, (vb.w + wrow * sum.w) * fs);
  ((float4*)a)[lf] = o;
  if (sig && d2) ((float4*)d2)[lf] = o;
}

extern "C" void kernel_launch(void* const* d_in, const int* in_sizes, int n_in,
                              void* d_out, int out_size, void* d_ws, size_t ws_size,
                              hipStream_t stream) {
  const float* spot_emb = (const float*)d_in[0];
  const float* user_emb = (const float*)d_in[1];
  const float* W1 = (const float*)d_in[2];
  const float* W2 = (const float*)d_in[3];
  const float* W3 = (const float*)d_in[4];
  const float* ew1 = (const float*)d_in[5];
  const float* ew2 = (const float*)d_in[6];
  const float* ew3 = (const float*)d_in[7];
  const int* us = (const int*)d_in[8];
  const int* ei1 = (const int*)d_in[9];
  const int* ei2 = (const int*)d_in[10];
  const int* ei3 = (const int*)d_in[11];

  const int M = in_sizes[0] / D;
  const int N = in_sizes[1] / D;
  const int EUS = in_sizes[8] / 2;
  const int ES1 = in_sizes[9] / 2;
  const int ES2 = in_sizes[10] / 2;
  const int ES3 = in_sizes[11] / 2;
  const int EStot = ES1 + ES2 + ES3;
  const int Etot = EUS + EStot;

  const int* uu = us;
  const int* ss = us + EUS;

  const size_t MD = (size_t)M * D, ND = (size_t)N * D;
  const int AM = (int)((M + 63) & ~63);

  float* cur = (float*)d_ws;
  auto take = [&](size_t n) { float* p = cur; cur += (n + 63) & ~(size_t)63; return p; };

  // contiguous zero group: count/cursor arrays
  int* rp_u = (int*)take(N);
  int* rp_s = (int*)take(M);
  int* grp = (int*)take((size_t)3 * M);
  float* zero_end = cur;
  float* dinv_u = take(N);
  float* dinv_s = take(M);
  float* gdinv = take((size_t)3 * AM);
  ushort* ue_s = (ushort*)take(EUS / 2 + 32);
  ushort* se_u = (ushort*)take(EUS / 2 + 32);
  uint* gsrc = (uint*)take(EStot);
  ushort* xw = (ushort*)take(MD / 2);
  uint2* UC_A = (uint2*)take(ND);
  uint2* UC_B = (uint2*)take(ND);
  uint2* SC_A = (uint2*)take(MD);
  uint2* SC_B = (uint2*)take(MD);

  ull* gpk = (ull*)UC_B;        // alias: gpk dead before UC_B first written (prop1)
  ushort* xw3 = (ushort*)UC_A;  // alias: UC_A dead after prop3

  float* out = (float*)d_out;
  float* o_so1 = out;
  float* o_uo1 = o_so1 + MD;
  float* o_so2 = o_uo1 + ND;
  float* o_uo2 = o_so2 + MD;
  float* o_so3 = o_uo2 + ND;
  float* o_uo3 = o_so3 + MD;

  const int B = 256;
  auto gr = [&](size_t work) { return (int)((work + B - 1) / B); };
  const int nbDeg = gr(Etot);
  const int nbPack = gr((size_t)(N + M) * 32);
  const int gProp = gr((size_t)(N + M) * 64);
  const int gM64 = gr((size_t)M * 64);
  const int gG = (M + 31) / 32;
  float* nulf = (float*)nullptr;

  hipMemsetAsync(rp_u, 0, (char*)zero_end - (char*)rp_u, stream);
  hipMemsetAsync(gpk, 0, (size_t)3 * AM * sizeof(ull), stream);

  // degrees + gemm1 (spot_emb @ W1 -> xw)
  k_front<<<nbDeg + gG, B, 0, stream>>>(uu, ss, EUS, ei1, ei2, ei3, ew1, ew2, ew3,
                                        ES1, ES2, ES3, rp_u, rp_s, gpk, AM, Etot,
                                        nbDeg, spot_emb, W1, xw, M);
  // exclusive starts + dinv tables
  k_scan5<<<5, 1024, 0, stream>>>(rp_u, rp_s, grp, gpk, dinv_u, dinv_s, gdinv, AM, N, M);
  // fills + dinv-scaled dual pack
  k_allfill<<<gr(Etot) + nbPack, B, 0, stream>>>(
      uu, ss, EUS, rp_u, rp_s, ue_s, se_u, ei1, ei2, ei3, ew1, ew2, ew3,
      ES1, ES2, ES3, gdinv, grp, gsrc, M, AM, Etot, gr(Etot),
      user_emb, spot_emb, dinv_u, dinv_s, (uint4*)UC_A, (uint4*)SC_A, N);

  // branch-1 conv: o_so1 = spot_emb + cat1; SC_A sig1 = dinv_s * o_so1
  k_gcn_gather<<<gM64, B, 0, stream>>>(grp, gsrc, gdinv, xw, spot_emb, o_so1,
                                       (uint*)SC_A, dinv_s, 1.0f, M);

  // prop layer 1 (+ gemm2: spot_emb @ W2 -> xw)
  k_prop_dual<<<gProp + gG, B, 0, stream>>>(rp_u, ue_s, rp_s, se_u, dinv_u, dinv_s,
                                            SC_A, UC_A, SC_B, UC_B,
                                            user_emb, user_emb, o_so1, spot_emb,
                                            o_uo1, o_uo2, o_so1, o_so2,
                                            nulf, nulf, 1.0f, 0, N, M,
                                            gProp, spot_emb, W2, xw, M);
  // prop layer 2
  k_prop_dual<<<gProp, B, 0, stream>>>(rp_u, ue_s, rp_s, se_u, dinv_u, dinv_s,
                                       SC_B, UC_B, SC_A, UC_A,
                                       o_uo1, o_uo2, o_so1, o_so2,
                                       o_uo1, o_uo2, o_so1, o_so2,
                                       nulf, nulf, 1.0f, 0, N, M,
                                       gProp, nulf, nulf, (ushort*)nullptr, M);
  // prop layer 3 (final: SC_B sig2 = raw fin_s; p duplicated to so3/uo3)
  k_prop_dual<<<gProp, B, 0, stream>>>(rp_u, ue_s, rp_s, se_u, dinv_u, dinv_s,
                                       SC_A, UC_A, SC_B, (uint2*)nullptr,
                                       o_uo1, o_uo2, o_so1, o_so2,
                                       o_uo1, o_uo2, o_so1, o_so2,
                                       o_uo3, o_so3, 0.25f, 1, N, M,
                                       gProp, nulf, nulf, (ushort*)nullptr, M);

  // tail: gemm3 (fin_s -> xw3) + gg2 (xw -> o_so2)
  k_tail<<<gG + gM64, B, 0, stream>>>(gG, DualHi{(const uint4*)SC_B}, W3, xw3, M,
                                      grp + M, gsrc + ES1, gdinv + AM, xw,
                                      o_so2, 0.25f, M);
  // branch 3: so3 += cat3/4
  k_gcn_gather<<<gM64, B, 0, stream>>>(grp + 2 * M, gsrc + ES1 + ES2, gdinv + 2 * AM,
                                       xw3, o_so3, o_so3, (uint*)nullptr,
                                       (const float*)nullptr, 0.25f, M);
}